// Round 6
// baseline (208.577 us; speedup 1.0000x reference)
//
#include <hip/hip_runtime.h>
#include <hip/hip_bf16.h>
#include <stdint.h>
#include <math.h>

#define T_SEQ 2048
#define NHEAD 16
#define CDIM 1024
#define QKV2_LD 2048   // packed q/k layout: head h -> q @ h*128, k @ h*128+64

typedef __attribute__((ext_vector_type(8))) short short8;
typedef __attribute__((ext_vector_type(4))) short short4v;
typedef __attribute__((ext_vector_type(4))) float floatx4;

static __device__ __forceinline__ short bf16b(float f) {
    __hip_bfloat16 h = __float2bfloat16(f);
    return __builtin_bit_cast(short, h);
}

// ---------------- fp32 -> bf16 cast ----------------
__global__ __launch_bounds__(256) void convert_f32_bf16(
    const float* __restrict__ in, __hip_bfloat16* __restrict__ out, int n)
{
    int i = (blockIdx.x * 256 + threadIdx.x) * 8;
    if (i >= n) return;
    float4 a = *(const float4*)(in + i);
    float4 b = *(const float4*)(in + i + 4);
    short8 o;
    o[0] = bf16b(a.x); o[1] = bf16b(a.y); o[2] = bf16b(a.z); o[3] = bf16b(a.w);
    o[4] = bf16b(b.x); o[5] = bf16b(b.y); o[6] = bf16b(b.z); o[7] = bf16b(b.w);
    *(short8*)(out + i) = o;
}

// ---------------- weight transpose+cast: in[R,C] fp32 -> out[C,R] bf16 ----------------
__global__ __launch_bounds__(256) void transpose_convert_kernel(
    const float* __restrict__ in, __hip_bfloat16* __restrict__ out,
    int R, int C)
{
    __shared__ short tile[64][65];
    const int r0 = blockIdx.y << 6;
    const int c0 = blockIdx.x << 6;
    const int tid = threadIdx.x;
    #pragma unroll
    for (int t = 0; t < 4; ++t) {
        int ch = t * 256 + tid;
        int rr = ch >> 4, cc = (ch & 15) << 2;
        float4 v = *(const float4*)(in + (size_t)(r0 + rr) * C + c0 + cc);
        tile[rr][cc + 0] = bf16b(v.x);
        tile[rr][cc + 1] = bf16b(v.y);
        tile[rr][cc + 2] = bf16b(v.z);
        tile[rr][cc + 3] = bf16b(v.w);
    }
    __syncthreads();
    #pragma unroll
    for (int t = 0; t < 2; ++t) {
        int ch = t * 256 + tid;
        int cc = ch >> 3, rr8 = (ch & 7) << 3;
        short8 v;
        #pragma unroll
        for (int j = 0; j < 8; ++j) v[j] = tile[rr8 + j][cc];
        *(short8*)(out + (size_t)(c0 + cc) * R + r0 + rr8) = v;
    }
}

// ---------------- GEMM: C = A @ Bt^T + bias; double-buffered, 1 barrier/k-iter ----------------
template <int MI, int NI, int MINW, bool QKV, typename OutT>
__global__ __launch_bounds__(256, MINW) void gemm_bias_kernel(
    const __hip_bfloat16* __restrict__ A,
    const __hip_bfloat16* __restrict__ Bt,
    const float* __restrict__ bias,
    OutT* __restrict__ C,
    __hip_bfloat16* __restrict__ vT,
    int M, int N, int K)
{
    __shared__ short As[2][MI * 32 * 64];
    __shared__ short Bs[2][NI * 32 * 64];
    const int tid  = threadIdx.x;
    const int lane = tid & 63;
    const int w    = tid >> 6;
    const int quad = lane >> 4;
    const int c16  = lane & 15;
    const int m0 = blockIdx.x * (MI * 32);
    const int n0 = blockIdx.y * (NI * 32);
    const int wm = (w >> 1) * (MI * 16);
    const int wn = (w & 1) * (NI * 16);

    floatx4 acc[MI][NI] = {};

    auto stage = [&](int kt, int bsel) {
        const int ktoff = kt * 64;
        #pragma unroll
        for (int r = 0; r < MI; ++r) {
            int ch = r * 256 + tid;
            int row = ch >> 3, k8 = (ch & 7) << 3;
            const __hip_bfloat16* ga = A + (size_t)(m0 + row) * K + ktoff + k8;
            __builtin_amdgcn_global_load_lds(
                (const __attribute__((address_space(1))) void*)ga,
                (__attribute__((address_space(3))) void*)&As[bsel][ch * 8], 16, 0, 0);
        }
        #pragma unroll
        for (int r = 0; r < NI; ++r) {
            int ch = r * 256 + tid;
            int row = ch >> 3, k8 = (ch & 7) << 3;
            const __hip_bfloat16* gb = Bt + (size_t)(n0 + row) * K + ktoff + k8;
            __builtin_amdgcn_global_load_lds(
                (const __attribute__((address_space(1))) void*)gb,
                (__attribute__((address_space(3))) void*)&Bs[bsel][ch * 8], 16, 0, 0);
        }
    };

    const int nk = K >> 6;
    stage(0, 0);
    int buf = 0;

    for (int kt = 0; kt < nk; ++kt) {
        __syncthreads();                         // drains vmcnt: buf ready; all waves synced
        if (kt + 1 < nk) stage(kt + 1, buf ^ 1); // prefetch has full compute window to land
        #pragma unroll
        for (int ko = 0; ko < 64; ko += 32) {
            short8 af[MI], bfr[NI];
            #pragma unroll
            for (int mi = 0; mi < MI; ++mi)
                af[mi] = *(const short8*)&As[buf][(wm + mi * 16 + c16) * 64 + ko + quad * 8];
            #pragma unroll
            for (int ni = 0; ni < NI; ++ni)
                bfr[ni] = *(const short8*)&Bs[buf][(wn + ni * 16 + c16) * 64 + ko + quad * 8];
            #pragma unroll
            for (int mi = 0; mi < MI; ++mi)
                #pragma unroll
                for (int ni = 0; ni < NI; ++ni)
                    acc[mi][ni] = __builtin_amdgcn_mfma_f32_16x16x32_bf16(
                        af[mi], bfr[ni], acc[mi][ni], 0, 0, 0);
        }
        buf ^= 1;
    }

    if constexpr (QKV) {
        const int colblk = (n0 + wn) >> 6;       // 64-col block is pure q/k/v
        const int head = colblk / 3;
        const int kind = colblk % 3;
        const int b    = m0 >> 11;
        if (kind == 2) {
            const size_t vbase = ((size_t)(b * 16 + head)) * 64 * T_SEQ;
            #pragma unroll
            for (int mi = 0; mi < MI; ++mi) {
                int t0 = ((m0 + wm + mi * 16) & 2047) + quad * 4;
                #pragma unroll
                for (int ni = 0; ni < NI; ++ni) {
                    int hd = ni * 16 + c16;
                    float bv = bias[n0 + wn + hd];
                    short4v pk;
                    #pragma unroll
                    for (int r2 = 0; r2 < 4; ++r2)
                        pk[r2] = bf16b(acc[mi][ni][r2] + bv);
                    *(short4v*)(vT + vbase + (size_t)hd * T_SEQ + t0) = pk;
                }
            }
        } else {
            const int cbase = head * 128 + kind * 64;
            #pragma unroll
            for (int mi = 0; mi < MI; ++mi)
                #pragma unroll
                for (int ni = 0; ni < NI; ++ni) {
                    float bv = bias[n0 + wn + ni * 16 + c16];
                    int col = cbase + ni * 16 + c16;
                    #pragma unroll
                    for (int r2 = 0; r2 < 4; ++r2) {
                        int row = m0 + wm + mi * 16 + quad * 4 + r2;
                        C[(size_t)row * QKV2_LD + col] = __float2bfloat16(acc[mi][ni][r2] + bv);
                    }
                }
        }
    } else {
        #pragma unroll
        for (int mi = 0; mi < MI; ++mi)
            #pragma unroll
            for (int ni = 0; ni < NI; ++ni) {
                int col = n0 + wn + ni * 16 + c16;
                float bv = bias[col];
                #pragma unroll
                for (int r2 = 0; r2 < 4; ++r2) {
                    int row = m0 + wm + mi * 16 + quad * 4 + r2;
                    float v = acc[mi][ni][r2] + bv;
                    if constexpr (__is_same(OutT, float)) {
                        C[(size_t)row * N + col] = v;
                    } else {
                        C[(size_t)row * N + col] = __float2bfloat16(v);
                    }
                }
            }
    }
}

// ---------------- fused causal flash attention ----------------
// k-tile 64: LDS = Ks 2x8K + Vs 2x8K + Pl 8K = 40 KB -> 4 blocks/CU (16 waves/CU).
// Same dbuf/1-barrier staging; no-max softmax; diag masking only on the last k-tile.
__global__ __launch_bounds__(256, 4) void attn_kernel(
    const __hip_bfloat16* __restrict__ qkv,   // [B*T,2048] packed; q @ h*128, k @ h*128+64
    const __hip_bfloat16* __restrict__ vT,    // [b*16+h][64][2048]
    __hip_bfloat16* __restrict__ attn_out)    // [B*T,1024]
{
    __shared__ short Ks[2][64 * 64];
    __shared__ short Vs[2][64 * 64];
    __shared__ short Pl[4][16 * 64];

    const int hb = blockIdx.x;
    const int qt = blockIdx.y;                // q-tile of 64, nkt = qt+1 k-tiles of 64
    const int h  = hb & 15;
    const int b  = hb >> 4;
    const int tid  = threadIdx.x;
    const int lane = tid & 63;
    const int w    = tid >> 6;
    const int quad = lane >> 4;
    const int c16  = lane & 15;

    const size_t rowbase = (size_t)b * T_SEQ;
    const size_t vbase   = (size_t)hb * 64 * T_SEQ;
    const int q0   = qt << 6;
    const int wrow = w << 4;
    const int hoff = h * 128;

    short8 qf[2];
    #pragma unroll
    for (int ko = 0; ko < 2; ++ko)
        qf[ko] = *(const short8*)(qkv +
            (rowbase + q0 + wrow + c16) * QKV2_LD + hoff + ko * 32 + quad * 8);

    floatx4 O[4] = {};
    floatx4 lpart = {0.f, 0.f, 0.f, 0.f};

    const float sc = 0.125f * 1.4426950408889634f;
    const int nkt = qt + 1;

    auto stage = [&](int kt, int bsel) {
        const int k0s = kt << 6;
        #pragma unroll
        for (int r = 0; r < 2; ++r) {
            int ch = r * 256 + tid;                       // K: 64 rows x 8 chunks
            int krow = ch >> 3;
            int hc = (ch & 7) ^ (krow & 7);
            const __hip_bfloat16* g = qkv + (rowbase + k0s + krow) * QKV2_LD + hoff + 64 + hc * 8;
            __builtin_amdgcn_global_load_lds(
                (const __attribute__((address_space(1))) void*)g,
                (__attribute__((address_space(3))) void*)&Ks[bsel][ch * 8], 16, 0, 0);
        }
        #pragma unroll
        for (int r = 0; r < 2; ++r) {
            int ch = r * 256 + tid;                       // V^T: 64 hd x 8 k-chunks
            int hd = ch >> 3;
            int kc = (ch & 7) ^ (hd & 7);
            const __hip_bfloat16* g = vT + vbase + (size_t)hd * T_SEQ + k0s + kc * 8;
            __builtin_amdgcn_global_load_lds(
                (const __attribute__((address_space(1))) void*)g,
                (__attribute__((address_space(3))) void*)&Vs[bsel][ch * 8], 16, 0, 0);
        }
    };

    stage(0, 0);
    int buf = 0;

    for (int kt = 0; kt < nkt; ++kt) {
        __syncthreads();
        if (kt + 1 < nkt) stage(kt + 1, buf ^ 1);

        // S = Q K^T : 4 krow-tiles of 16
        floatx4 S[4] = {};
        #pragma unroll
        for (int ko = 0; ko < 2; ++ko) {
            short8 kf[4];
            #pragma unroll
            for (int ni = 0; ni < 4; ++ni)
                kf[ni] = *(const short8*)&Ks[buf][(ni * 16 + c16) * 64 +
                                                 (((4 * ko + quad) ^ (c16 & 7)) << 3)];
            #pragma unroll
            for (int ni = 0; ni < 4; ++ni)
                S[ni] = __builtin_amdgcn_mfma_f32_16x16x32_bf16(qf[ko], kf[ni], S[ni], 0, 0, 0);
        }

        // p = exp2(s*sc); mask only on diagonal tile (wave-uniform branch)
        if (kt == nkt - 1) {
            #pragma unroll
            for (int ni = 0; ni < 4; ++ni)
                #pragma unroll
                for (int r = 0; r < 4; ++r) {
                    bool msk = (ni * 16 + c16 > wrow + quad * 4 + r);
                    float p = msk ? 0.f : exp2f(S[ni][r] * sc);
                    S[ni][r] = p;
                    lpart[r] += p;
                }
        } else {
            #pragma unroll
            for (int ni = 0; ni < 4; ++ni)
                #pragma unroll
                for (int r = 0; r < 4; ++r) {
                    float p = exp2f(S[ni][r] * sc);
                    S[ni][r] = p;
                    lpart[r] += p;
                }
        }

        // P: C-layout -> per-wave LDS, chunk-swizzled (2-way max = free)
        #pragma unroll
        for (int ni = 0; ni < 4; ++ni)
            #pragma unroll
            for (int r = 0; r < 4; ++r) {
                int row = quad * 4 + r, col = ni * 16 + c16;
                Pl[w][row * 64 + (((col >> 3) ^ (row & 7)) << 3) + (col & 7)] = bf16b(S[ni][r]);
            }

        // O += P @ V  (contraction over 64 kpos = 2 k-steps)
        #pragma unroll
        for (int ko = 0; ko < 2; ++ko) {
            short8 pa = *(const short8*)&Pl[w][c16 * 64 + (((4 * ko + quad) ^ (c16 & 7)) << 3)];
            short8 vb[4];
            #pragma unroll
            for (int ni = 0; ni < 4; ++ni)
                vb[ni] = *(const short8*)&Vs[buf][(ni * 16 + c16) * 64 +
                                                 (((4 * ko + quad) ^ (c16 & 7)) << 3)];
            #pragma unroll
            for (int ni = 0; ni < 4; ++ni)
                O[ni] = __builtin_amdgcn_mfma_f32_16x16x32_bf16(pa, vb[ni], O[ni], 0, 0, 0);
        }
        buf ^= 1;
    }

    // epilogue: single l-reduction + normalize
    #pragma unroll
    for (int r = 0; r < 4; ++r) {
        float l = lpart[r];
        l += __shfl_xor(l, 1);
        l += __shfl_xor(l, 2);
        l += __shfl_xor(l, 4);
        l += __shfl_xor(l, 8);
        float inv = 1.0f / l;
        size_t row = rowbase + q0 + wrow + quad * 4 + r;
        #pragma unroll
        for (int ni = 0; ni < 4; ++ni)
            attn_out[row * CDIM + h * 64 + ni * 16 + c16] =
                __float2bfloat16(O[ni][r] * inv);
    }
}

extern "C" void kernel_launch(void* const* d_in, const int* in_sizes, int n_in,
                              void* d_out, int out_size, void* d_ws, size_t ws_size,
                              hipStream_t stream) {
    const float* x     = (const float*)d_in[0];
    const float* Wqkv  = (const float*)d_in[1];
    const float* bqkv  = (const float*)d_in[2];
    const float* Wproj = (const float*)d_in[3];
    const float* bproj = (const float*)d_in[4];
    float* out = (float*)d_out;

    __hip_bfloat16* xb     = (__hip_bfloat16*)d_ws;
    __hip_bfloat16* WqkvT  = xb     + (size_t)4096 * 1024;
    __hip_bfloat16* WprojT = WqkvT  + (size_t)3072 * 1024;
    __hip_bfloat16* qkv2   = WprojT + (size_t)1024 * 1024;
    __hip_bfloat16* vT     = qkv2   + (size_t)4096 * 2048;
    __hip_bfloat16* attn   = vT     + (size_t)32 * 64 * 2048;

    convert_f32_bf16<<<4096 * 1024 / 2048, 256, 0, stream>>>(x, xb, 4096 * 1024);
    transpose_convert_kernel<<<dim3(3072 / 64, 1024 / 64), 256, 0, stream>>>(Wqkv, WqkvT, 1024, 3072);
    transpose_convert_kernel<<<dim3(1024 / 64, 1024 / 64), 256, 0, stream>>>(Wproj, WprojT, 1024, 1024);
    gemm_bias_kernel<4, 4, 2, true, __hip_bfloat16>
        <<<dim3(4096 / 128, 3072 / 128), 256, 0, stream>>>(
        xb, WqkvT, bqkv, qkv2, vT, 4096, 3072, 1024);
    attn_kernel<<<dim3(32, 32), 256, 0, stream>>>(qkv2, vT, attn);
    gemm_bias_kernel<4, 2, 3, false, float>
        <<<dim3(4096 / 128, 1024 / 64), 256, 0, stream>>>(
        attn, WprojT, bproj, out, nullptr, 4096, 1024, 1024);
}

// Round 8
// 181.880 us; speedup vs baseline: 1.1468x; 1.1468x over previous
//
#include <hip/hip_runtime.h>
#include <hip/hip_bf16.h>
#include <stdint.h>
#include <math.h>

#define T_SEQ 2048
#define NHEAD 16
#define CDIM 1024
#define QKV2_LD 2048   // packed q/k layout: head h -> q @ h*128, k @ h*128+64

typedef __attribute__((ext_vector_type(8))) short short8;
typedef __attribute__((ext_vector_type(4))) short short4v;
typedef __attribute__((ext_vector_type(4))) float floatx4;

static __device__ __forceinline__ short bf16b(float f) {
    __hip_bfloat16 h = __float2bfloat16(f);
    return __builtin_bit_cast(short, h);
}

// ---------------- fp32 -> bf16 cast ----------------
__global__ __launch_bounds__(256) void convert_f32_bf16(
    const float* __restrict__ in, __hip_bfloat16* __restrict__ out, int n)
{
    int i = (blockIdx.x * 256 + threadIdx.x) * 8;
    if (i >= n) return;
    float4 a = *(const float4*)(in + i);
    float4 b = *(const float4*)(in + i + 4);
    short8 o;
    o[0] = bf16b(a.x); o[1] = bf16b(a.y); o[2] = bf16b(a.z); o[3] = bf16b(a.w);
    o[4] = bf16b(b.x); o[5] = bf16b(b.y); o[6] = bf16b(b.z); o[7] = bf16b(b.w);
    *(short8*)(out + i) = o;
}

// ---------------- weight transpose+cast: in[R,C] fp32 -> out[C,R] bf16 ----------------
__global__ __launch_bounds__(256) void transpose_convert_kernel(
    const float* __restrict__ in, __hip_bfloat16* __restrict__ out,
    int R, int C)
{
    __shared__ short tile[64][65];
    const int r0 = blockIdx.y << 6;
    const int c0 = blockIdx.x << 6;
    const int tid = threadIdx.x;
    #pragma unroll
    for (int t = 0; t < 4; ++t) {
        int ch = t * 256 + tid;
        int rr = ch >> 4, cc = (ch & 15) << 2;
        float4 v = *(const float4*)(in + (size_t)(r0 + rr) * C + c0 + cc);
        tile[rr][cc + 0] = bf16b(v.x);
        tile[rr][cc + 1] = bf16b(v.y);
        tile[rr][cc + 2] = bf16b(v.z);
        tile[rr][cc + 3] = bf16b(v.w);
    }
    __syncthreads();
    #pragma unroll
    for (int t = 0; t < 2; ++t) {
        int ch = t * 256 + tid;
        int cc = ch >> 3, rr8 = (ch & 7) << 3;
        short8 v;
        #pragma unroll
        for (int j = 0; j < 8; ++j) v[j] = tile[rr8 + j][cc];
        *(short8*)(out + (size_t)(c0 + cc) * R + r0 + rr8) = v;
    }
}

// ---------------- GEMM (round-5 proven structure: single-buffer, 2-barrier) ----------------
template <int MI, int NI, int MINW, bool QKV, typename OutT>
__global__ __launch_bounds__(256, MINW) void gemm_bias_kernel(
    const __hip_bfloat16* __restrict__ A,
    const __hip_bfloat16* __restrict__ Bt,
    const float* __restrict__ bias,
    OutT* __restrict__ C,
    __hip_bfloat16* __restrict__ vT,
    int M, int N, int K)
{
    __shared__ short As[MI * 32 * 64];
    __shared__ short Bs[NI * 32 * 64];
    const int tid  = threadIdx.x;
    const int lane = tid & 63;
    const int w    = tid >> 6;
    const int quad = lane >> 4;
    const int c16  = lane & 15;
    const int m0 = blockIdx.x * (MI * 32);
    const int n0 = blockIdx.y * (NI * 32);
    const int wm = (w >> 1) * (MI * 16);
    const int wn = (w & 1) * (NI * 16);

    floatx4 acc[MI][NI] = {};

    for (int kt = 0; kt < K; kt += 64) {
        __syncthreads();
        #pragma unroll
        for (int r = 0; r < MI; ++r) {
            int ch = r * 256 + tid;
            int row = ch >> 3, k8 = (ch & 7) << 3;
            const __hip_bfloat16* ga = A + (size_t)(m0 + row) * K + kt + k8;
            __builtin_amdgcn_global_load_lds(
                (const __attribute__((address_space(1))) void*)ga,
                (__attribute__((address_space(3))) void*)&As[ch * 8], 16, 0, 0);
        }
        #pragma unroll
        for (int r = 0; r < NI; ++r) {
            int ch = r * 256 + tid;
            int row = ch >> 3, k8 = (ch & 7) << 3;
            const __hip_bfloat16* gb = Bt + (size_t)(n0 + row) * K + kt + k8;
            __builtin_amdgcn_global_load_lds(
                (const __attribute__((address_space(1))) void*)gb,
                (__attribute__((address_space(3))) void*)&Bs[ch * 8], 16, 0, 0);
        }
        __syncthreads();
        #pragma unroll
        for (int ko = 0; ko < 64; ko += 32) {
            short8 af[MI], bfr[NI];
            #pragma unroll
            for (int mi = 0; mi < MI; ++mi)
                af[mi] = *(const short8*)&As[(wm + mi * 16 + c16) * 64 + ko + quad * 8];
            #pragma unroll
            for (int ni = 0; ni < NI; ++ni)
                bfr[ni] = *(const short8*)&Bs[(wn + ni * 16 + c16) * 64 + ko + quad * 8];
            #pragma unroll
            for (int mi = 0; mi < MI; ++mi)
                #pragma unroll
                for (int ni = 0; ni < NI; ++ni)
                    acc[mi][ni] = __builtin_amdgcn_mfma_f32_16x16x32_bf16(
                        af[mi], bfr[ni], acc[mi][ni], 0, 0, 0);
        }
    }

    if constexpr (QKV) {
        const int colblk = (n0 + wn) >> 6;
        const int head = colblk / 3;
        const int kind = colblk % 3;
        const int b    = m0 >> 11;
        if (kind == 2) {
            const size_t vbase = ((size_t)(b * 16 + head)) * 64 * T_SEQ;
            #pragma unroll
            for (int mi = 0; mi < MI; ++mi) {
                int t0 = ((m0 + wm + mi * 16) & 2047) + quad * 4;
                #pragma unroll
                for (int ni = 0; ni < NI; ++ni) {
                    int hd = ni * 16 + c16;
                    float bv = bias[n0 + wn + hd];
                    short4v pk;
                    #pragma unroll
                    for (int r2 = 0; r2 < 4; ++r2)
                        pk[r2] = bf16b(acc[mi][ni][r2] + bv);
                    *(short4v*)(vT + vbase + (size_t)hd * T_SEQ + t0) = pk;
                }
            }
        } else {
            const int cbase = head * 128 + kind * 64;
            #pragma unroll
            for (int mi = 0; mi < MI; ++mi)
                #pragma unroll
                for (int ni = 0; ni < NI; ++ni) {
                    float bv = bias[n0 + wn + ni * 16 + c16];
                    int col = cbase + ni * 16 + c16;
                    #pragma unroll
                    for (int r2 = 0; r2 < 4; ++r2) {
                        int row = m0 + wm + mi * 16 + quad * 4 + r2;
                        C[(size_t)row * QKV2_LD + col] = __float2bfloat16(acc[mi][ni][r2] + bv);
                    }
                }
        }
    } else {
        #pragma unroll
        for (int mi = 0; mi < MI; ++mi)
            #pragma unroll
            for (int ni = 0; ni < NI; ++ni) {
                int col = n0 + wn + ni * 16 + c16;
                float bv = bias[col];
                #pragma unroll
                for (int r2 = 0; r2 < 4; ++r2) {
                    int row = m0 + wm + mi * 16 + quad * 4 + r2;
                    float v = acc[mi][ni][r2] + bv;
                    if constexpr (__is_same(OutT, float)) {
                        C[(size_t)row * N + col] = v;
                    } else {
                        C[(size_t)row * N + col] = __float2bfloat16(v);
                    }
                }
            }
    }
}

// ---------------- fused causal flash attention (S^T form, paired q-tiles) ----------------
// Block handles q-tiles {p, 31-p} (uniform 33 tile-computes). S^T = K·Q^T so each lane
// owns one q-row (c16) and 4 consecutive kpos per reg -> packed b64 P-writes, scalar l.
// K/V staged dbuf via global_load_lds, shared by both q-tiles. LDS 48 KB.
__global__ __launch_bounds__(256, 2) void attn_kernel(
    const __hip_bfloat16* __restrict__ qkv,   // [B*T,2048] packed; q @ h*128, k @ h*128+64
    const __hip_bfloat16* __restrict__ vT,    // [b*16+h][64][2048]
    __hip_bfloat16* __restrict__ attn_out)    // [B*T,1024]
{
    __shared__ short Ks[2][64 * 64];
    __shared__ short Vs[2][64 * 64];
    __shared__ short Pl[4][2][16 * 64];

    const int hb = blockIdx.x;
    const int p  = blockIdx.y;                // 0..15
    const int h  = hb & 15;
    const int b  = hb >> 4;
    const int tid  = threadIdx.x;
    const int lane = tid & 63;
    const int w    = tid >> 6;
    const int quad = lane >> 4;
    const int c16  = lane & 15;

    const size_t rowbase = (size_t)b * T_SEQ;
    const size_t vbase   = (size_t)hb * 64 * T_SEQ;
    const int qtA = p, qtB = 31 - p;
    const int q0A = qtA << 6, q0B = qtB << 6;
    const int wrow = w << 4;
    const int hoff = h * 128;
    const int key  = c16 & 7;

    short8 qfA[2], qfB[2];
    #pragma unroll
    for (int ko = 0; ko < 2; ++ko) {
        qfA[ko] = *(const short8*)(qkv +
            (rowbase + q0A + wrow + c16) * QKV2_LD + hoff + ko * 32 + quad * 8);
        qfB[ko] = *(const short8*)(qkv +
            (rowbase + q0B + wrow + c16) * QKV2_LD + hoff + ko * 32 + quad * 8);
    }

    floatx4 OA[4] = {}, OB[4] = {};
    float lpA = 0.f, lpB = 0.f;
    const float sc = 0.125f * 1.4426950408889634f;
    const int nkt = qtB + 1;

    auto stage = [&](int kt, int bsel) {
        const int k0s = kt << 6;
        #pragma unroll
        for (int r = 0; r < 2; ++r) {
            int ch = r * 256 + tid;
            int krow = ch >> 3;
            int hc = (ch & 7) ^ (krow & 7);
            const __hip_bfloat16* g = qkv + (rowbase + k0s + krow) * QKV2_LD + hoff + 64 + hc * 8;
            __builtin_amdgcn_global_load_lds(
                (const __attribute__((address_space(1))) void*)g,
                (__attribute__((address_space(3))) void*)&Ks[bsel][ch * 8], 16, 0, 0);
        }
        #pragma unroll
        for (int r = 0; r < 2; ++r) {
            int ch = r * 256 + tid;
            int hd = ch >> 3;
            int kc = (ch & 7) ^ (hd & 7);
            const __hip_bfloat16* g = vT + vbase + (size_t)hd * T_SEQ + k0s + kc * 8;
            __builtin_amdgcn_global_load_lds(
                (const __attribute__((address_space(1))) void*)g,
                (__attribute__((address_space(3))) void*)&Vs[bsel][ch * 8], 16, 0, 0);
        }
    };

    stage(0, 0);
    int buf = 0;

    for (int kt = 0; kt < nkt; ++kt) {
        __syncthreads();
        if (kt + 1 < nkt) stage(kt + 1, buf ^ 1);

        // shared K / V fragments for this k-tile (reused by both q-tiles)
        short8 kf[2][4], vb[2][4];
        #pragma unroll
        for (int ko = 0; ko < 2; ++ko)
            #pragma unroll
            for (int ni = 0; ni < 4; ++ni) {
                int sl = ((4 * ko + quad) ^ key) << 3;
                kf[ko][ni] = *(const short8*)&Ks[buf][(ni * 16 + c16) * 64 + sl];
                vb[ko][ni] = *(const short8*)&Vs[buf][(ni * 16 + c16) * 64 + sl];
            }

        // process one q-tile: S^T = K Q^T -> exp2 -> P(b64-packed) -> O^T += V^T P^T
        auto process = [&](const short8 (&qf)[2], floatx4 (&O)[4], float& lp,
                           bool diag, short* Pw) {
            floatx4 S[4] = {};
            #pragma unroll
            for (int ko = 0; ko < 2; ++ko)
                #pragma unroll
                for (int ni = 0; ni < 4; ++ni)
                    S[ni] = __builtin_amdgcn_mfma_f32_16x16x32_bf16(
                        kf[ko][ni], qf[ko], S[ni], 0, 0, 0);
            if (diag) {
                #pragma unroll
                for (int ni = 0; ni < 4; ++ni)
                    #pragma unroll
                    for (int r = 0; r < 4; ++r) {
                        bool msk = (ni * 16 + quad * 4 + r) > (wrow + c16);
                        float pe = msk ? 0.f : exp2f(S[ni][r] * sc);
                        S[ni][r] = pe;
                        lp += pe;
                    }
            } else {
                #pragma unroll
                for (int ni = 0; ni < 4; ++ni)
                    #pragma unroll
                    for (int r = 0; r < 4; ++r) {
                        float pe = exp2f(S[ni][r] * sc);
                        S[ni][r] = pe;
                        lp += pe;
                    }
            }
            // packed P write: row c16, kpos chunk8 = ni*2+(quad>>1), swizzled by key
            #pragma unroll
            for (int ni = 0; ni < 4; ++ni) {
                short4v pk;
                #pragma unroll
                for (int r = 0; r < 4; ++r) pk[r] = bf16b(S[ni][r]);
                int pair = ni * 2 + (quad >> 1);
                int off = c16 * 64 + ((((pair ^ key) << 1) + (quad & 1)) << 2);
                *(short4v*)&Pw[off] = pk;
            }
            // O^T += V^T · P^T  (A = V^T frag, B = P row-c16 b128 reads, chunk8 swizzled)
            #pragma unroll
            for (int ko = 0; ko < 2; ++ko) {
                int off = c16 * 64 + (((ko * 4 + quad) ^ key) << 3);   // FIX: <<3 (8 shorts/chunk)
                short8 pa = *(const short8*)&Pw[off];
                #pragma unroll
                for (int ni = 0; ni < 4; ++ni)
                    O[ni] = __builtin_amdgcn_mfma_f32_16x16x32_bf16(
                        vb[ko][ni], pa, O[ni], 0, 0, 0);
            }
        };

        process(qfB, OB, lpB, kt == qtB, &Pl[w][1][0]);
        if (kt <= qtA) process(qfA, OA, lpA, kt == qtA, &Pl[w][0][0]);
        buf ^= 1;
    }

    // epilogue: lane-local l, reduce across quads, packed b64 stores
    auto finish = [&](floatx4 (&O)[4], float lp, int q0) {
        float l = lp;
        l += __shfl_xor(l, 16);
        l += __shfl_xor(l, 32);
        float inv = 1.0f / l;
        size_t row = rowbase + q0 + wrow + c16;
        #pragma unroll
        for (int ni = 0; ni < 4; ++ni) {
            short4v o;
            #pragma unroll
            for (int r = 0; r < 4; ++r) o[r] = bf16b(O[ni][r] * inv);
            *(short4v*)(attn_out + row * CDIM + h * 64 + ni * 16 + quad * 4) = o;
        }
    };
    finish(OA, lpA, q0A);
    finish(OB, lpB, q0B);
}

extern "C" void kernel_launch(void* const* d_in, const int* in_sizes, int n_in,
                              void* d_out, int out_size, void* d_ws, size_t ws_size,
                              hipStream_t stream) {
    const float* x     = (const float*)d_in[0];
    const float* Wqkv  = (const float*)d_in[1];
    const float* bqkv  = (const float*)d_in[2];
    const float* Wproj = (const float*)d_in[3];
    const float* bproj = (const float*)d_in[4];
    float* out = (float*)d_out;

    __hip_bfloat16* xb     = (__hip_bfloat16*)d_ws;
    __hip_bfloat16* WqkvT  = xb     + (size_t)4096 * 1024;
    __hip_bfloat16* WprojT = WqkvT  + (size_t)3072 * 1024;
    __hip_bfloat16* qkv2   = WprojT + (size_t)1024 * 1024;
    __hip_bfloat16* vT     = qkv2   + (size_t)4096 * 2048;
    __hip_bfloat16* attn   = vT     + (size_t)32 * 64 * 2048;

    convert_f32_bf16<<<4096 * 1024 / 2048, 256, 0, stream>>>(x, xb, 4096 * 1024);
    transpose_convert_kernel<<<dim3(3072 / 64, 1024 / 64), 256, 0, stream>>>(Wqkv, WqkvT, 1024, 3072);
    transpose_convert_kernel<<<dim3(1024 / 64, 1024 / 64), 256, 0, stream>>>(Wproj, WprojT, 1024, 1024);
    gemm_bias_kernel<4, 4, 2, true, __hip_bfloat16>
        <<<dim3(4096 / 128, 3072 / 128), 256, 0, stream>>>(
        xb, WqkvT, bqkv, qkv2, vT, 4096, 3072, 1024);
    attn_kernel<<<dim3(32, 16), 256, 0, stream>>>(qkv2, vT, attn);
    gemm_bias_kernel<4, 2, 2, false, float>
        <<<dim3(4096 / 128, 1024 / 64), 256, 0, stream>>>(
        attn, WprojT, bproj, out, nullptr, 4096, 1024, 1024);
}

// Round 9
// 178.000 us; speedup vs baseline: 1.1718x; 1.0218x over previous
//
#include <hip/hip_runtime.h>
#include <hip/hip_bf16.h>
#include <stdint.h>
#include <math.h>

#define T_SEQ 2048
#define NHEAD 16
#define CDIM 1024
#define QKV2_LD 2048   // packed q/k layout: head h -> q @ h*128, k @ h*128+64

typedef __attribute__((ext_vector_type(8))) short short8;
typedef __attribute__((ext_vector_type(4))) short short4v;
typedef __attribute__((ext_vector_type(4))) float floatx4;

static __device__ __forceinline__ short bf16b(float f) {
    __hip_bfloat16 h = __float2bfloat16(f);
    return __builtin_bit_cast(short, h);
}

// ---------------- fused prep: x cast + W transposes (one launch) ----------------
// blocks [0,2048): convert x (fp32->bf16); [2048,2816): Wqkv^T; [2816,3072): Wproj^T
__device__ __forceinline__ void transpose_body(
    const float* __restrict__ in, __hip_bfloat16* __restrict__ out,
    int R, int C, int bx, int by, int tid)
{
    __shared__ short tile[64][65];
    const int r0 = by << 6;
    const int c0 = bx << 6;
    #pragma unroll
    for (int t = 0; t < 4; ++t) {
        int ch = t * 256 + tid;
        int rr = ch >> 4, cc = (ch & 15) << 2;
        float4 v = *(const float4*)(in + (size_t)(r0 + rr) * C + c0 + cc);
        tile[rr][cc + 0] = bf16b(v.x);
        tile[rr][cc + 1] = bf16b(v.y);
        tile[rr][cc + 2] = bf16b(v.z);
        tile[rr][cc + 3] = bf16b(v.w);
    }
    __syncthreads();
    #pragma unroll
    for (int t = 0; t < 2; ++t) {
        int ch = t * 256 + tid;
        int cc = ch >> 3, rr8 = (ch & 7) << 3;
        short8 v;
        #pragma unroll
        for (int j = 0; j < 8; ++j) v[j] = tile[rr8 + j][cc];
        *(short8*)(out + (size_t)(c0 + cc) * R + r0 + rr8) = v;
    }
}

__global__ __launch_bounds__(256) void prep_kernel(
    const float* __restrict__ x,     __hip_bfloat16* __restrict__ xb,
    const float* __restrict__ Wqkv,  __hip_bfloat16* __restrict__ WqkvT,
    const float* __restrict__ Wproj, __hip_bfloat16* __restrict__ WprojT)
{
    const int bid = blockIdx.x;
    const int tid = threadIdx.x;
    if (bid < 2048) {
        int i = (bid * 256 + tid) * 8;
        float4 a = *(const float4*)(x + i);
        float4 b = *(const float4*)(x + i + 4);
        short8 o;
        o[0] = bf16b(a.x); o[1] = bf16b(a.y); o[2] = bf16b(a.z); o[3] = bf16b(a.w);
        o[4] = bf16b(b.x); o[5] = bf16b(b.y); o[6] = bf16b(b.z); o[7] = bf16b(b.w);
        *(short8*)(xb + i) = o;
    } else if (bid < 2816) {
        int r = bid - 2048;                      // 768 blocks: C=3072 (48) x R=1024 (16)
        transpose_body(Wqkv, WqkvT, 1024, 3072, r % 48, r / 48, tid);
    } else {
        int r = bid - 2816;                      // 256 blocks: 16 x 16
        transpose_body(Wproj, WprojT, 1024, 1024, r & 15, r >> 4, tid);
    }
}

// ---------------- GEMM (single-buffer, 2-barrier; QKV epilogue w/ LDS-transposed v) ----
template <int MI, int NI, int MINW, bool QKV, typename OutT>
__global__ __launch_bounds__(256, MINW) void gemm_bias_kernel(
    const __hip_bfloat16* __restrict__ A,
    const __hip_bfloat16* __restrict__ Bt,
    const float* __restrict__ bias,
    OutT* __restrict__ C,
    __hip_bfloat16* __restrict__ vT,
    int M, int N, int K)
{
    __shared__ short As[MI * 32 * 64];
    __shared__ short Bs[NI * 32 * 64];
    const int tid  = threadIdx.x;
    const int lane = tid & 63;
    const int w    = tid >> 6;
    const int quad = lane >> 4;
    const int c16  = lane & 15;
    const int m0 = blockIdx.x * (MI * 32);
    const int n0 = blockIdx.y * (NI * 32);
    const int wm = (w >> 1) * (MI * 16);
    const int wn = (w & 1) * (NI * 16);

    floatx4 acc[MI][NI] = {};

    for (int kt = 0; kt < K; kt += 64) {
        __syncthreads();
        #pragma unroll
        for (int r = 0; r < MI; ++r) {
            int ch = r * 256 + tid;
            int row = ch >> 3, k8 = (ch & 7) << 3;
            const __hip_bfloat16* ga = A + (size_t)(m0 + row) * K + kt + k8;
            __builtin_amdgcn_global_load_lds(
                (const __attribute__((address_space(1))) void*)ga,
                (__attribute__((address_space(3))) void*)&As[ch * 8], 16, 0, 0);
        }
        #pragma unroll
        for (int r = 0; r < NI; ++r) {
            int ch = r * 256 + tid;
            int row = ch >> 3, k8 = (ch & 7) << 3;
            const __hip_bfloat16* gb = Bt + (size_t)(n0 + row) * K + kt + k8;
            __builtin_amdgcn_global_load_lds(
                (const __attribute__((address_space(1))) void*)gb,
                (__attribute__((address_space(3))) void*)&Bs[ch * 8], 16, 0, 0);
        }
        __syncthreads();
        #pragma unroll
        for (int ko = 0; ko < 64; ko += 32) {
            short8 af[MI], bfr[NI];
            #pragma unroll
            for (int mi = 0; mi < MI; ++mi)
                af[mi] = *(const short8*)&As[(wm + mi * 16 + c16) * 64 + ko + quad * 8];
            #pragma unroll
            for (int ni = 0; ni < NI; ++ni)
                bfr[ni] = *(const short8*)&Bs[(wn + ni * 16 + c16) * 64 + ko + quad * 8];
            #pragma unroll
            for (int mi = 0; mi < MI; ++mi)
                #pragma unroll
                for (int ni = 0; ni < NI; ++ni)
                    acc[mi][ni] = __builtin_amdgcn_mfma_f32_16x16x32_bf16(
                        af[mi], bfr[ni], acc[mi][ni], 0, 0, 0);
        }
    }

    if constexpr (QKV) {
        const int colblk = (n0 + wn) >> 6;
        const int head = colblk / 3;
        const int kind = colblk % 3;
        const int b    = m0 >> 11;
        __syncthreads();                       // all waves done with As/Bs LDS
        if (kind == 2) {
            // transpose 64x64 tile via LDS (chunk4 XOR swizzle), coalesced vT stores
            short* tp = (w < 2) ? &As[w * 4096] : &Bs[(w - 2) * 4096];
            #pragma unroll
            for (int mi = 0; mi < MI; ++mi)
                #pragma unroll
                for (int ni = 0; ni < NI; ++ni) {
                    int hd = ni * 16 + c16;
                    float bv = bias[n0 + wn + hd];
                    short4v pk;
                    #pragma unroll
                    for (int r2 = 0; r2 < 4; ++r2) pk[r2] = bf16b(acc[mi][ni][r2] + bv);
                    int tc = mi * 4 + quad;    // t-chunk4 within the wave's 64 rows
                    *(short4v*)&tp[hd * 64 + ((tc ^ ((hd & 7) << 1)) << 2)] = pk;
                }
            const size_t vb2 = ((size_t)(b * 16 + head)) * 64 * T_SEQ;
            const int t0 = (m0 + wm) & 2047;
            #pragma unroll
            for (int it = 0; it < 8; ++it) {
                int hd = it * 8 + (lane >> 3);
                int tc2 = (lane & 7) << 1;
                short8 vv = *(const short8*)&tp[hd * 64 + ((tc2 ^ ((hd & 7) << 1)) << 2)];
                *(short8*)(vT + vb2 + (size_t)hd * T_SEQ + t0 + ((lane & 7) << 3)) = vv;
            }
        } else {
            const int cbase = head * 128 + kind * 64;
            #pragma unroll
            for (int mi = 0; mi < MI; ++mi)
                #pragma unroll
                for (int ni = 0; ni < NI; ++ni) {
                    float bv = bias[n0 + wn + ni * 16 + c16];
                    int col = cbase + ni * 16 + c16;
                    #pragma unroll
                    for (int r2 = 0; r2 < 4; ++r2) {
                        int row = m0 + wm + mi * 16 + quad * 4 + r2;
                        C[(size_t)row * QKV2_LD + col] = __float2bfloat16(acc[mi][ni][r2] + bv);
                    }
                }
        }
    } else {
        #pragma unroll
        for (int mi = 0; mi < MI; ++mi)
            #pragma unroll
            for (int ni = 0; ni < NI; ++ni) {
                int col = n0 + wn + ni * 16 + c16;
                float bv = bias[col];
                #pragma unroll
                for (int r2 = 0; r2 < 4; ++r2) {
                    int row = m0 + wm + mi * 16 + quad * 4 + r2;
                    float v = acc[mi][ni][r2] + bv;
                    if constexpr (__is_same(OutT, float)) {
                        C[(size_t)row * N + col] = v;
                    } else {
                        C[(size_t)row * N + col] = __float2bfloat16(v);
                    }
                }
            }
    }
}

// ---------------- fused causal flash attention (S^T form, paired q-tiles) ----------------
__global__ __launch_bounds__(256, 2) void attn_kernel(
    const __hip_bfloat16* __restrict__ qkv,   // [B*T,2048] packed; q @ h*128, k @ h*128+64
    const __hip_bfloat16* __restrict__ vT,    // [b*16+h][64][2048]
    __hip_bfloat16* __restrict__ attn_out)    // [B*T,1024]
{
    __shared__ short Ks[2][64 * 64];
    __shared__ short Vs[2][64 * 64];
    __shared__ short Pl[4][16 * 64];          // one region per wave (wave-private, serial reuse)

    const int hb = blockIdx.x;
    const int p  = blockIdx.y;                // 0..15
    const int h  = hb & 15;
    const int b  = hb >> 4;
    const int tid  = threadIdx.x;
    const int lane = tid & 63;
    const int w    = tid >> 6;
    const int quad = lane >> 4;
    const int c16  = lane & 15;

    const size_t rowbase = (size_t)b * T_SEQ;
    const size_t vbase   = (size_t)hb * 64 * T_SEQ;
    const int qtA = p, qtB = 31 - p;
    const int q0A = qtA << 6, q0B = qtB << 6;
    const int wrow = w << 4;
    const int hoff = h * 128;
    const int key  = c16 & 7;

    short8 qfA[2], qfB[2];
    #pragma unroll
    for (int ko = 0; ko < 2; ++ko) {
        qfA[ko] = *(const short8*)(qkv +
            (rowbase + q0A + wrow + c16) * QKV2_LD + hoff + ko * 32 + quad * 8);
        qfB[ko] = *(const short8*)(qkv +
            (rowbase + q0B + wrow + c16) * QKV2_LD + hoff + ko * 32 + quad * 8);
    }

    floatx4 OA[4] = {}, OB[4] = {};
    float lpA = 0.f, lpB = 0.f;
    const float sc = 0.125f * 1.4426950408889634f;
    const int nkt = qtB + 1;

    auto stage = [&](int kt, int bsel) {
        const int k0s = kt << 6;
        #pragma unroll
        for (int r = 0; r < 2; ++r) {
            int ch = r * 256 + tid;
            int krow = ch >> 3;
            int hc = (ch & 7) ^ (krow & 7);
            const __hip_bfloat16* g = qkv + (rowbase + k0s + krow) * QKV2_LD + hoff + 64 + hc * 8;
            __builtin_amdgcn_global_load_lds(
                (const __attribute__((address_space(1))) void*)g,
                (__attribute__((address_space(3))) void*)&Ks[bsel][ch * 8], 16, 0, 0);
        }
        #pragma unroll
        for (int r = 0; r < 2; ++r) {
            int ch = r * 256 + tid;
            int hd = ch >> 3;
            int kc = (ch & 7) ^ (hd & 7);
            const __hip_bfloat16* g = vT + vbase + (size_t)hd * T_SEQ + k0s + kc * 8;
            __builtin_amdgcn_global_load_lds(
                (const __attribute__((address_space(1))) void*)g,
                (__attribute__((address_space(3))) void*)&Vs[bsel][ch * 8], 16, 0, 0);
        }
    };

    stage(0, 0);
    int buf = 0;

    for (int kt = 0; kt < nkt; ++kt) {
        __syncthreads();
        if (kt + 1 < nkt) stage(kt + 1, buf ^ 1);

        short8 kf[2][4], vb[2][4];
        #pragma unroll
        for (int ko = 0; ko < 2; ++ko)
            #pragma unroll
            for (int ni = 0; ni < 4; ++ni) {
                int sl = ((4 * ko + quad) ^ key) << 3;
                kf[ko][ni] = *(const short8*)&Ks[buf][(ni * 16 + c16) * 64 + sl];
                vb[ko][ni] = *(const short8*)&Vs[buf][(ni * 16 + c16) * 64 + sl];
            }

        auto process = [&](const short8 (&qf)[2], floatx4 (&O)[4], float& lp, bool diag) {
            short* Pw = &Pl[w][0];
            floatx4 S[4] = {};
            #pragma unroll
            for (int ko = 0; ko < 2; ++ko)
                #pragma unroll
                for (int ni = 0; ni < 4; ++ni)
                    S[ni] = __builtin_amdgcn_mfma_f32_16x16x32_bf16(
                        kf[ko][ni], qf[ko], S[ni], 0, 0, 0);
            if (diag) {
                #pragma unroll
                for (int ni = 0; ni < 4; ++ni)
                    #pragma unroll
                    for (int r = 0; r < 4; ++r) {
                        bool msk = (ni * 16 + quad * 4 + r) > (wrow + c16);
                        float pe = msk ? 0.f : exp2f(S[ni][r] * sc);
                        S[ni][r] = pe;
                        lp += pe;
                    }
            } else {
                #pragma unroll
                for (int ni = 0; ni < 4; ++ni)
                    #pragma unroll
                    for (int r = 0; r < 4; ++r) {
                        float pe = exp2f(S[ni][r] * sc);
                        S[ni][r] = pe;
                        lp += pe;
                    }
            }
            #pragma unroll
            for (int ni = 0; ni < 4; ++ni) {
                short4v pk;
                #pragma unroll
                for (int r = 0; r < 4; ++r) pk[r] = bf16b(S[ni][r]);
                int pair = ni * 2 + (quad >> 1);
                int off = c16 * 64 + ((((pair ^ key) << 1) + (quad & 1)) << 2);
                *(short4v*)&Pw[off] = pk;
            }
            #pragma unroll
            for (int ko = 0; ko < 2; ++ko) {
                int off = c16 * 64 + (((ko * 4 + quad) ^ key) << 3);
                short8 pa = *(const short8*)&Pw[off];
                #pragma unroll
                for (int ni = 0; ni < 4; ++ni)
                    O[ni] = __builtin_amdgcn_mfma_f32_16x16x32_bf16(
                        vb[ko][ni], pa, O[ni], 0, 0, 0);
            }
        };

        process(qfB, OB, lpB, kt == qtB);
        if (kt <= qtA) process(qfA, OA, lpA, kt == qtA);
        buf ^= 1;
    }

    auto finish = [&](floatx4 (&O)[4], float lp, int q0) {
        float l = lp;
        l += __shfl_xor(l, 16);
        l += __shfl_xor(l, 32);
        float inv = 1.0f / l;
        size_t row = rowbase + q0 + wrow + c16;
        #pragma unroll
        for (int ni = 0; ni < 4; ++ni) {
            short4v o;
            #pragma unroll
            for (int r = 0; r < 4; ++r) o[r] = bf16b(O[ni][r] * inv);
            *(short4v*)(attn_out + row * CDIM + h * 64 + ni * 16 + quad * 4) = o;
        }
    };
    finish(OA, lpA, q0A);
    finish(OB, lpB, q0B);
}

extern "C" void kernel_launch(void* const* d_in, const int* in_sizes, int n_in,
                              void* d_out, int out_size, void* d_ws, size_t ws_size,
                              hipStream_t stream) {
    const float* x     = (const float*)d_in[0];
    const float* Wqkv  = (const float*)d_in[1];
    const float* bqkv  = (const float*)d_in[2];
    const float* Wproj = (const float*)d_in[3];
    const float* bproj = (const float*)d_in[4];
    float* out = (float*)d_out;

    __hip_bfloat16* xb     = (__hip_bfloat16*)d_ws;
    __hip_bfloat16* WqkvT  = xb     + (size_t)4096 * 1024;
    __hip_bfloat16* WprojT = WqkvT  + (size_t)3072 * 1024;
    __hip_bfloat16* qkv2   = WprojT + (size_t)1024 * 1024;
    __hip_bfloat16* vT     = qkv2   + (size_t)4096 * 2048;
    __hip_bfloat16* attn   = vT     + (size_t)32 * 64 * 2048;

    prep_kernel<<<3072, 256, 0, stream>>>(x, xb, Wqkv, WqkvT, Wproj, WprojT);
    gemm_bias_kernel<4, 4, 2, true, __hip_bfloat16>
        <<<dim3(4096 / 128, 3072 / 128), 256, 0, stream>>>(
        xb, WqkvT, bqkv, qkv2, vT, 4096, 3072, 1024);
    attn_kernel<<<dim3(32, 16), 256, 0, stream>>>(qkv2, vT, attn);
    gemm_bias_kernel<2, 2, 4, false, float>
        <<<dim3(4096 / 64, 1024 / 64), 256, 0, stream>>>(
        attn, WprojT, bproj, out, nullptr, 4096, 1024, 1024);
}

// Round 10
// 177.149 us; speedup vs baseline: 1.1774x; 1.0048x over previous
//
#include <hip/hip_runtime.h>
#include <hip/hip_bf16.h>
#include <stdint.h>
#include <math.h>

#define T_SEQ 2048
#define NHEAD 16
#define CDIM 1024
#define QKV2_LD 2048   // packed q/k layout: head h -> q @ h*128, k @ h*128+64

typedef __attribute__((ext_vector_type(8))) short short8;
typedef __attribute__((ext_vector_type(4))) short short4v;
typedef __attribute__((ext_vector_type(4))) float floatx4;

static __device__ __forceinline__ short bf16b(float f) {
    __hip_bfloat16 h = __float2bfloat16(f);
    return __builtin_bit_cast(short, h);
}

// ---------------- fused prep: x cast + W transposes (one launch) ----------------
__device__ __forceinline__ void transpose_body(
    const float* __restrict__ in, __hip_bfloat16* __restrict__ out,
    int R, int C, int bx, int by, int tid)
{
    __shared__ short tile[64][65];
    const int r0 = by << 6;
    const int c0 = bx << 6;
    #pragma unroll
    for (int t = 0; t < 4; ++t) {
        int ch = t * 256 + tid;
        int rr = ch >> 4, cc = (ch & 15) << 2;
        float4 v = *(const float4*)(in + (size_t)(r0 + rr) * C + c0 + cc);
        tile[rr][cc + 0] = bf16b(v.x);
        tile[rr][cc + 1] = bf16b(v.y);
        tile[rr][cc + 2] = bf16b(v.z);
        tile[rr][cc + 3] = bf16b(v.w);
    }
    __syncthreads();
    #pragma unroll
    for (int t = 0; t < 2; ++t) {
        int ch = t * 256 + tid;
        int cc = ch >> 3, rr8 = (ch & 7) << 3;
        short8 v;
        #pragma unroll
        for (int j = 0; j < 8; ++j) v[j] = tile[rr8 + j][cc];
        *(short8*)(out + (size_t)(c0 + cc) * R + r0 + rr8) = v;
    }
}

__global__ __launch_bounds__(256) void prep_kernel(
    const float* __restrict__ x,     __hip_bfloat16* __restrict__ xb,
    const float* __restrict__ Wqkv,  __hip_bfloat16* __restrict__ WqkvT,
    const float* __restrict__ Wproj, __hip_bfloat16* __restrict__ WprojT)
{
    const int bid = blockIdx.x;
    const int tid = threadIdx.x;
    if (bid < 2048) {
        int i = (bid * 256 + tid) * 8;
        float4 a = *(const float4*)(x + i);
        float4 b = *(const float4*)(x + i + 4);
        short8 o;
        o[0] = bf16b(a.x); o[1] = bf16b(a.y); o[2] = bf16b(a.z); o[3] = bf16b(a.w);
        o[4] = bf16b(b.x); o[5] = bf16b(b.y); o[6] = bf16b(b.z); o[7] = bf16b(b.w);
        *(short8*)(xb + i) = o;
    } else if (bid < 2816) {
        int r = bid - 2048;
        transpose_body(Wqkv, WqkvT, 1024, 3072, r % 48, r / 48, tid);
    } else {
        int r = bid - 2816;
        transpose_body(Wproj, WprojT, 1024, 1024, r & 15, r >> 4, tid);
    }
}

// ---------------- GEMM (single-buffer, 2-barrier; QKV epilogue w/ LDS-transposed v) ----
template <int MI, int NI, int MINW, bool QKV, typename OutT>
__global__ __launch_bounds__(256, MINW) void gemm_bias_kernel(
    const __hip_bfloat16* __restrict__ A,
    const __hip_bfloat16* __restrict__ Bt,
    const float* __restrict__ bias,
    OutT* __restrict__ C,
    __hip_bfloat16* __restrict__ vT,
    int M, int N, int K)
{
    __shared__ short As[MI * 32 * 64];
    __shared__ short Bs[NI * 32 * 64];
    const int tid  = threadIdx.x;
    const int lane = tid & 63;
    const int w    = tid >> 6;
    const int quad = lane >> 4;
    const int c16  = lane & 15;
    const int m0 = blockIdx.x * (MI * 32);
    const int n0 = blockIdx.y * (NI * 32);
    const int wm = (w >> 1) * (MI * 16);
    const int wn = (w & 1) * (NI * 16);

    floatx4 acc[MI][NI] = {};

    for (int kt = 0; kt < K; kt += 64) {
        __syncthreads();
        #pragma unroll
        for (int r = 0; r < MI; ++r) {
            int ch = r * 256 + tid;
            int row = ch >> 3, k8 = (ch & 7) << 3;
            const __hip_bfloat16* ga = A + (size_t)(m0 + row) * K + kt + k8;
            __builtin_amdgcn_global_load_lds(
                (const __attribute__((address_space(1))) void*)ga,
                (__attribute__((address_space(3))) void*)&As[ch * 8], 16, 0, 0);
        }
        #pragma unroll
        for (int r = 0; r < NI; ++r) {
            int ch = r * 256 + tid;
            int row = ch >> 3, k8 = (ch & 7) << 3;
            const __hip_bfloat16* gb = Bt + (size_t)(n0 + row) * K + kt + k8;
            __builtin_amdgcn_global_load_lds(
                (const __attribute__((address_space(1))) void*)gb,
                (__attribute__((address_space(3))) void*)&Bs[ch * 8], 16, 0, 0);
        }
        __syncthreads();
        #pragma unroll
        for (int ko = 0; ko < 64; ko += 32) {
            short8 af[MI], bfr[NI];
            #pragma unroll
            for (int mi = 0; mi < MI; ++mi)
                af[mi] = *(const short8*)&As[(wm + mi * 16 + c16) * 64 + ko + quad * 8];
            #pragma unroll
            for (int ni = 0; ni < NI; ++ni)
                bfr[ni] = *(const short8*)&Bs[(wn + ni * 16 + c16) * 64 + ko + quad * 8];
            #pragma unroll
            for (int mi = 0; mi < MI; ++mi)
                #pragma unroll
                for (int ni = 0; ni < NI; ++ni)
                    acc[mi][ni] = __builtin_amdgcn_mfma_f32_16x16x32_bf16(
                        af[mi], bfr[ni], acc[mi][ni], 0, 0, 0);
        }
    }

    if constexpr (QKV) {
        const int colblk = (n0 + wn) >> 6;
        const int head = colblk / 3;
        const int kind = colblk % 3;
        const int b    = m0 >> 11;
        __syncthreads();
        if (kind == 2) {
            short* tp = (w < 2) ? &As[w * 4096] : &Bs[(w - 2) * 4096];
            #pragma unroll
            for (int mi = 0; mi < MI; ++mi)
                #pragma unroll
                for (int ni = 0; ni < NI; ++ni) {
                    int hd = ni * 16 + c16;
                    float bv = bias[n0 + wn + hd];
                    short4v pk;
                    #pragma unroll
                    for (int r2 = 0; r2 < 4; ++r2) pk[r2] = bf16b(acc[mi][ni][r2] + bv);
                    int tc = mi * 4 + quad;
                    *(short4v*)&tp[hd * 64 + ((tc ^ ((hd & 7) << 1)) << 2)] = pk;
                }
            const size_t vb2 = ((size_t)(b * 16 + head)) * 64 * T_SEQ;
            const int t0 = (m0 + wm) & 2047;
            #pragma unroll
            for (int it = 0; it < 8; ++it) {
                int hd = it * 8 + (lane >> 3);
                int tc2 = (lane & 7) << 1;
                short8 vv = *(const short8*)&tp[hd * 64 + ((tc2 ^ ((hd & 7) << 1)) << 2)];
                *(short8*)(vT + vb2 + (size_t)hd * T_SEQ + t0 + ((lane & 7) << 3)) = vv;
            }
        } else {
            const int cbase = head * 128 + kind * 64;
            #pragma unroll
            for (int mi = 0; mi < MI; ++mi)
                #pragma unroll
                for (int ni = 0; ni < NI; ++ni) {
                    float bv = bias[n0 + wn + ni * 16 + c16];
                    int col = cbase + ni * 16 + c16;
                    #pragma unroll
                    for (int r2 = 0; r2 < 4; ++r2) {
                        int row = m0 + wm + mi * 16 + quad * 4 + r2;
                        C[(size_t)row * QKV2_LD + col] = __float2bfloat16(acc[mi][ni][r2] + bv);
                    }
                }
        }
    } else {
        #pragma unroll
        for (int mi = 0; mi < MI; ++mi)
            #pragma unroll
            for (int ni = 0; ni < NI; ++ni) {
                int col = n0 + wn + ni * 16 + c16;
                float bv = bias[col];
                #pragma unroll
                for (int r2 = 0; r2 < 4; ++r2) {
                    int row = m0 + wm + mi * 16 + quad * 4 + r2;
                    float v = acc[mi][ni][r2] + bv;
                    if constexpr (__is_same(OutT, float)) {
                        C[(size_t)row * N + col] = v;
                    } else {
                        C[(size_t)row * N + col] = __float2bfloat16(v);
                    }
                }
            }
    }
}

// ---------------- fused causal flash attention (S^T form, unpaired + LPT) ----------------
// One q-tile of 64 per block; grid (hb=32, 32) = 1024 blocks -> 4 blocks/CU (LDS 40 KB).
// qt = 31 - blockIdx.y: longest blocks dispatch first (LPT), short blocks backfill tail.
__global__ __launch_bounds__(256, 4) void attn_kernel(
    const __hip_bfloat16* __restrict__ qkv,   // [B*T,2048] packed; q @ h*128, k @ h*128+64
    const __hip_bfloat16* __restrict__ vT,    // [b*16+h][64][2048]
    __hip_bfloat16* __restrict__ attn_out)    // [B*T,1024]
{
    __shared__ short Ks[2][64 * 64];
    __shared__ short Vs[2][64 * 64];
    __shared__ short Pl[4][16 * 64];          // wave-private, serial reuse

    const int hb = blockIdx.x;
    const int qt = 31 - blockIdx.y;           // LPT ordering
    const int h  = hb & 15;
    const int b  = hb >> 4;
    const int tid  = threadIdx.x;
    const int lane = tid & 63;
    const int w    = tid >> 6;
    const int quad = lane >> 4;
    const int c16  = lane & 15;

    const size_t rowbase = (size_t)b * T_SEQ;
    const size_t vbase   = (size_t)hb * 64 * T_SEQ;
    const int q0   = qt << 6;
    const int wrow = w << 4;
    const int hoff = h * 128;
    const int key  = c16 & 7;

    short8 qf[2];
    #pragma unroll
    for (int ko = 0; ko < 2; ++ko)
        qf[ko] = *(const short8*)(qkv +
            (rowbase + q0 + wrow + c16) * QKV2_LD + hoff + ko * 32 + quad * 8);

    floatx4 O[4] = {};
    float lp = 0.f;
    const float sc = 0.125f * 1.4426950408889634f;
    const int nkt = qt + 1;

    auto stage = [&](int kt, int bsel) {
        const int k0s = kt << 6;
        #pragma unroll
        for (int r = 0; r < 2; ++r) {
            int ch = r * 256 + tid;
            int krow = ch >> 3;
            int hc = (ch & 7) ^ (krow & 7);
            const __hip_bfloat16* g = qkv + (rowbase + k0s + krow) * QKV2_LD + hoff + 64 + hc * 8;
            __builtin_amdgcn_global_load_lds(
                (const __attribute__((address_space(1))) void*)g,
                (__attribute__((address_space(3))) void*)&Ks[bsel][ch * 8], 16, 0, 0);
        }
        #pragma unroll
        for (int r = 0; r < 2; ++r) {
            int ch = r * 256 + tid;
            int hd = ch >> 3;
            int kc = (ch & 7) ^ (hd & 7);
            const __hip_bfloat16* g = vT + vbase + (size_t)hd * T_SEQ + k0s + kc * 8;
            __builtin_amdgcn_global_load_lds(
                (const __attribute__((address_space(1))) void*)g,
                (__attribute__((address_space(3))) void*)&Vs[bsel][ch * 8], 16, 0, 0);
        }
    };

    stage(0, 0);
    int buf = 0;

    for (int kt = 0; kt < nkt; ++kt) {
        __syncthreads();
        if (kt + 1 < nkt) stage(kt + 1, buf ^ 1);

        short8 kf[2][4], vb[2][4];
        #pragma unroll
        for (int ko = 0; ko < 2; ++ko)
            #pragma unroll
            for (int ni = 0; ni < 4; ++ni) {
                int sl = ((4 * ko + quad) ^ key) << 3;
                kf[ko][ni] = *(const short8*)&Ks[buf][(ni * 16 + c16) * 64 + sl];
                vb[ko][ni] = *(const short8*)&Vs[buf][(ni * 16 + c16) * 64 + sl];
            }

        short* Pw = &Pl[w][0];
        floatx4 S[4] = {};
        #pragma unroll
        for (int ko = 0; ko < 2; ++ko)
            #pragma unroll
            for (int ni = 0; ni < 4; ++ni)
                S[ni] = __builtin_amdgcn_mfma_f32_16x16x32_bf16(
                    kf[ko][ni], qf[ko], S[ni], 0, 0, 0);

        if (kt == qt) {
            #pragma unroll
            for (int ni = 0; ni < 4; ++ni)
                #pragma unroll
                for (int r = 0; r < 4; ++r) {
                    bool msk = (ni * 16 + quad * 4 + r) > (wrow + c16);
                    float pe = msk ? 0.f : exp2f(S[ni][r] * sc);
                    S[ni][r] = pe;
                    lp += pe;
                }
        } else {
            #pragma unroll
            for (int ni = 0; ni < 4; ++ni)
                #pragma unroll
                for (int r = 0; r < 4; ++r) {
                    float pe = exp2f(S[ni][r] * sc);
                    S[ni][r] = pe;
                    lp += pe;
                }
        }

        #pragma unroll
        for (int ni = 0; ni < 4; ++ni) {
            short4v pk;
            #pragma unroll
            for (int r = 0; r < 4; ++r) pk[r] = bf16b(S[ni][r]);
            int pair = ni * 2 + (quad >> 1);
            int off = c16 * 64 + ((((pair ^ key) << 1) + (quad & 1)) << 2);
            *(short4v*)&Pw[off] = pk;
        }

        #pragma unroll
        for (int ko = 0; ko < 2; ++ko) {
            int off = c16 * 64 + (((ko * 4 + quad) ^ key) << 3);
            short8 pa = *(const short8*)&Pw[off];
            #pragma unroll
            for (int ni = 0; ni < 4; ++ni)
                O[ni] = __builtin_amdgcn_mfma_f32_16x16x32_bf16(
                    vb[ko][ni], pa, O[ni], 0, 0, 0);
        }
        buf ^= 1;
    }

    // epilogue: lane-local l, reduce across quads, packed b64 stores
    float l = lp;
    l += __shfl_xor(l, 16);
    l += __shfl_xor(l, 32);
    float inv = 1.0f / l;
    size_t row = rowbase + q0 + wrow + c16;
    #pragma unroll
    for (int ni = 0; ni < 4; ++ni) {
        short4v o;
        #pragma unroll
        for (int r = 0; r < 4; ++r) o[r] = bf16b(O[ni][r] * inv);
        *(short4v*)(attn_out + row * CDIM + h * 64 + ni * 16 + quad * 4) = o;
    }
}

extern "C" void kernel_launch(void* const* d_in, const int* in_sizes, int n_in,
                              void* d_out, int out_size, void* d_ws, size_t ws_size,
                              hipStream_t stream) {
    const float* x     = (const float*)d_in[0];
    const float* Wqkv  = (const float*)d_in[1];
    const float* bqkv  = (const float*)d_in[2];
    const float* Wproj = (const float*)d_in[3];
    const float* bproj = (const float*)d_in[4];
    float* out = (float*)d_out;

    __hip_bfloat16* xb     = (__hip_bfloat16*)d_ws;
    __hip_bfloat16* WqkvT  = xb     + (size_t)4096 * 1024;
    __hip_bfloat16* WprojT = WqkvT  + (size_t)3072 * 1024;
    __hip_bfloat16* qkv2   = WprojT + (size_t)1024 * 1024;
    __hip_bfloat16* vT     = qkv2   + (size_t)4096 * 2048;
    __hip_bfloat16* attn   = vT     + (size_t)32 * 64 * 2048;

    prep_kernel<<<3072, 256, 0, stream>>>(x, xb, Wqkv, WqkvT, Wproj, WprojT);
    gemm_bias_kernel<4, 4, 2, true, __hip_bfloat16>
        <<<dim3(4096 / 128, 3072 / 128), 256, 0, stream>>>(
        xb, WqkvT, bqkv, qkv2, vT, 4096, 3072, 1024);
    attn_kernel<<<dim3(32, 32), 256, 0, stream>>>(qkv2, vT, attn);
    gemm_bias_kernel<2, 2, 4, false, float>
        <<<dim3(4096 / 64, 1024 / 64), 256, 0, stream>>>(
        attn, WprojT, bproj, out, nullptr, 4096, 1024, 1024);
}